// Round 7
// baseline (520.755 us; speedup 1.0000x reference)
//
#include <hip/hip_runtime.h>

#define HID   64
#define ENC_T 20
#define DEC_T 30
#define HS    72   // sH row stride in bf16 elems: 144B = 16B-aligned
#define PS    36   // sP row stride in dwords
#define NT    4    // independent 16-row tiles per block (one per wave at epilogue)

typedef __bf16 bf16x8 __attribute__((ext_vector_type(8)));
typedef float  f32x4  __attribute__((ext_vector_type(4)));
typedef float  f32x2  __attribute__((ext_vector_type(2)));
typedef unsigned int u32x2 __attribute__((ext_vector_type(2)));
typedef unsigned short ushort_t;
typedef unsigned int   uint_t;

#if __has_builtin(__builtin_amdgcn_exp2f)
#define EXP2F(x) __builtin_amdgcn_exp2f(x)
#else
#define EXP2F(x) exp2f(x)
#endif
#if __has_builtin(__builtin_amdgcn_rcpf)
#define RCPF(x) __builtin_amdgcn_rcpf(x)
#else
#define RCPF(x) (1.0f / (x))
#endif

#define L2E 1.4426950408889634f

__device__ __forceinline__ ushort_t f2bf(float f) {
    __bf16 b = (__bf16)f;
    union { __bf16 b; ushort_t u; } v; v.b = b; return v.u;
}

struct bfpair { bf16x8 hi, lo; };

// Split 8 consecutive fp32 (scaled by s) into bf16 hi + lo fragments (setup only)
__device__ __forceinline__ bfpair split8s(const float* __restrict__ p, float s) {
    unsigned short h[8], l[8];
    #pragma unroll
    for (int u = 0; u < 8; ++u) {
        float f = p[u] * s;
        __bf16 bh = (__bf16)f;
        h[u] = f2bf(f);
        l[u] = f2bf(f - (float)bh);
    }
    bfpair r;
    __builtin_memcpy(&r.hi, h, 16);
    __builtin_memcpy(&r.lo, l, 16);
    return r;
}

// __launch_bounds__(256,1): empirical law (R3/R5/R6): RA allocates VGPRs for
// ~2x the min-waves hint (hint3->84, hint4->64, hint5->48). Quad-tile needs
// ~200 regs -> hint=1 (RA target ~256). FETCH_SIZE is the spill tripwire.
__global__ __launch_bounds__(256, 1)
void lstm_seq2seq(const float* __restrict__ traj,
                  const float* __restrict__ WihE, const float* __restrict__ WhhE,
                  const float* __restrict__ bihE, const float* __restrict__ bhhE,
                  const float* __restrict__ WihD, const float* __restrict__ WhhD,
                  const float* __restrict__ bihD, const float* __restrict__ bhhD,
                  const float* __restrict__ Wpos, const float* __restrict__ bpos,
                  float* __restrict__ out)
{
    // NT independent 16-row tiles per block: intra-wave MFMA/VALU overlap,
    // barriers amortized NT-fold. LDS = 64 KB -> 2 blocks/CU.
    __shared__ __align__(16) ushort_t sHh[NT][2][16 * HS];  // [tile][buf][row*HS+unit]
    __shared__ __align__(16) ushort_t sHl[NT][2][16 * HS];
    __shared__ __align__(16) float    sX[NT][16 * ENC_T * 2];
    __shared__ __align__(16) float    sP[NT][2][16 * PS];   // [tile][buf]

    const int tid  = threadIdx.x;
    const int w    = tid >> 6;      // wave -> unit tile (units 16w..16w+15)
    const int lane = tid & 63;
    const int col  = lane & 15;     // batch row within each 16-row tile
    const int quad = lane >> 4;     // units 16w + quad*4 + r
    const int wg   = blockIdx.x;    // 64 batch rows per block

    const float gsc[4] = { L2E, L2E, 2.0f * L2E, L2E };  // i,f,g(tanh),o pre-scales

    // ---- stage trajectory tile: 2560 contiguous floats (rows 64wg..64wg+63) ----
    {
        const float* src = traj + (size_t)wg * (NT * 16 * ENC_T * 2);
        float* dst = &sX[0][0];
        #pragma unroll
        for (int i = 0; i < NT * 16 * ENC_T * 2 / 256; ++i)
            dst[tid + i * 256] = src[tid + i * 256];
    }
    // ---- zero all h buffers (h0 = 0; zeroing both bufs is cheap, once) ----
    {
        uint_t* hz0 = (uint_t*)&sHh[0][0][0];
        uint_t* hz1 = (uint_t*)&sHl[0][0][0];
        for (int j = tid; j < NT * 2 * 16 * HS / 2; j += 256) { hz0[j] = 0; hz1[j] = 0; }
    }

    // ---- encoder per-lane constants (shared across tiles) ----
    float wi0[4][4], wi1[4][4], bE[4][4];
    #pragma unroll
    for (int j = 0; j < 4; ++j)
        #pragma unroll
        for (int r = 0; r < 4; ++r) {
            int g = 64 * j + 16 * w + quad * 4 + r;
            wi0[j][r] = WihE[g * 2 + 0] * gsc[j];
            wi1[j][r] = WihE[g * 2 + 1] * gsc[j];
            bE[j][r]  = (bihE[g] + bhhE[g]) * gsc[j];
        }

    // ---- encoder W_hh A-fragments (shared across tiles) ----
    bfpair bw[4][2];
    #pragma unroll
    for (int j = 0; j < 4; ++j) {
        int g = 64 * j + 16 * w + col;
        #pragma unroll
        for (int kb = 0; kb < 2; ++kb)
            bw[j][kb] = split8s(WhhE + g * 64 + kb * 32 + quad * 8, gsc[j]);
    }

    float c[NT][4];
    #pragma unroll
    for (int tl = 0; tl < NT; ++tl)
        #pragma unroll
        for (int r = 0; r < 4; ++r) c[tl][r] = 0.f;
    int buf = 0;
    const int hwr = col * HS + 16 * w + quad * 4;   // h write offset within tile
    const int hrd0 = col * HS + quad * 8;           // h read offsets
    const int hrd1 = col * HS + 32 + quad * 8;

    __syncthreads();

    // =========================== ENCODER ===========================
    for (int t = 0; t < ENC_T; ++t) {
        f32x4 acc[NT][4];
        bf16x8 b0h[NT], b1h[NT], b0l[NT], b1l[NT];
        #pragma unroll
        for (int tl = 0; tl < NT; ++tl) {
            b0h[tl] = *(const bf16x8*)&sHh[tl][buf][hrd0];
            b1h[tl] = *(const bf16x8*)&sHh[tl][buf][hrd1];
            b0l[tl] = *(const bf16x8*)&sHl[tl][buf][hrd0];
            b1l[tl] = *(const bf16x8*)&sHl[tl][buf][hrd1];
            f32x2 xp = *(const f32x2*)&sX[tl][col * (ENC_T * 2) + 2 * t];
            #pragma unroll
            for (int j = 0; j < 4; ++j)
                #pragma unroll
                for (int r = 0; r < 4; ++r)
                    acc[tl][j][r] = fmaf(wi1[j][r], xp[1], fmaf(wi0[j][r], xp[0], bE[j][r]));
        }
        #pragma unroll
        for (int tl = 0; tl < NT; ++tl)
            #pragma unroll
            for (int j = 0; j < 4; ++j) {
                acc[tl][j] = __builtin_amdgcn_mfma_f32_16x16x32_bf16(bw[j][0].hi, b0l[tl], acc[tl][j], 0, 0, 0);
                acc[tl][j] = __builtin_amdgcn_mfma_f32_16x16x32_bf16(bw[j][1].hi, b1l[tl], acc[tl][j], 0, 0, 0);
                acc[tl][j] = __builtin_amdgcn_mfma_f32_16x16x32_bf16(bw[j][0].lo, b0h[tl], acc[tl][j], 0, 0, 0);
                acc[tl][j] = __builtin_amdgcn_mfma_f32_16x16x32_bf16(bw[j][1].lo, b1h[tl], acc[tl][j], 0, 0, 0);
                acc[tl][j] = __builtin_amdgcn_mfma_f32_16x16x32_bf16(bw[j][0].hi, b0h[tl], acc[tl][j], 0, 0, 0);
                acc[tl][j] = __builtin_amdgcn_mfma_f32_16x16x32_bf16(bw[j][1].hi, b1h[tl], acc[tl][j], 0, 0, 0);
            }
        #pragma unroll
        for (int tl = 0; tl < NT; ++tl) {
            uint_t hhp[2], hlp[2];
            #pragma unroll
            for (int rp = 0; rp < 2; ++rp) {
                int r0 = rp * 2, r1 = rp * 2 + 1;
                f32x2 ei = { EXP2F(-acc[tl][0][r0]), EXP2F(-acc[tl][0][r1]) };
                f32x2 ef = { EXP2F(-acc[tl][1][r0]), EXP2F(-acc[tl][1][r1]) };
                f32x2 eg = { EXP2F(-acc[tl][2][r0]), EXP2F(-acc[tl][2][r1]) };
                f32x2 eo = { EXP2F(-acc[tl][3][r0]), EXP2F(-acc[tl][3][r1]) };
                ei = ei + 1.0f; ef = ef + 1.0f; eg = eg + 1.0f; eo = eo + 1.0f;
                f32x2 ig = { RCPF(ei[0]), RCPF(ei[1]) };
                f32x2 fg = { RCPF(ef[0]), RCPF(ef[1]) };
                f32x2 gr = { RCPF(eg[0]), RCPF(eg[1]) };
                f32x2 og = { RCPF(eo[0]), RCPF(eo[1]) };
                f32x2 gg = 2.0f * gr - 1.0f;
                f32x2 cv = { c[tl][r0], c[tl][r1] };
                f32x2 cn = fg * cv + ig * gg;
                c[tl][r0] = cn[0]; c[tl][r1] = cn[1];
                f32x2 ca = cn * (-2.0f * L2E);
                f32x2 ec = { EXP2F(ca[0]), EXP2F(ca[1]) };
                ec = ec + 1.0f;
                f32x2 tr = { RCPF(ec[0]), RCPF(ec[1]) };
                f32x2 th = 2.0f * tr - 1.0f;
                f32x2 hn = og * th;
                uint_t u0 = __float_as_uint(hn[0]);
                uint_t u1 = __float_as_uint(hn[1]);
                f32x2 fh = { __uint_as_float(u0 & 0xffff0000u),
                             __uint_as_float(u1 & 0xffff0000u) };
                hhp[rp] = (u0 >> 16) | (u1 & 0xffff0000u);
                f32x2 lo = hn - fh;
                hlp[rp] = (uint_t)f2bf(lo[0]) | ((uint_t)f2bf(lo[1]) << 16);
            }
            *(u32x2*)&sHh[tl][buf ^ 1][hwr] = u32x2{hhp[0], hhp[1]};
            *(u32x2*)&sHl[tl][buf ^ 1][hwr] = u32x2{hlp[0], hlp[1]};
        }
        __syncthreads();
        buf ^= 1;
    }

    // ---- decoder combined weights (shared across tiles) ----
    f32x4 bD4[4];
    #pragma unroll
    for (int j = 0; j < 4; ++j) {
        #pragma unroll
        for (int r = 0; r < 4; ++r) {
            int g = 64 * j + 16 * w + quad * 4 + r;
            bD4[j][r] = (bihD[g] + bhhD[g]) * gsc[j];
        }
        int g = 64 * j + 16 * w + col;
        #pragma unroll
        for (int kb = 0; kb < 2; ++kb) {
            int off = g * 64 + kb * 32 + quad * 8;
            float tmp[8];
            #pragma unroll
            for (int u = 0; u < 8; ++u) tmp[u] = WihD[off + u] + WhhD[off + u];
            bw[j][kb] = split8s(tmp, gsc[j]);
        }
    }

    // projection constants: this lane's 4 units -> {comp0, comp1} pairs
    f32x2 wpP[4];
    #pragma unroll
    for (int r = 0; r < 4; ++r) {
        int u = 16 * w + quad * 4 + r;
        wpP[r] = f32x2{ Wpos[u], Wpos[64 + u] };
    }
    const int prow  = lane & 15;
    const int pcomp = (lane >> 4) & 1;
    const float bp  = bpos[pcomp];

    // =========================== DECODER ===========================
    for (int t = 0; t < DEC_T; ++t) {
        f32x4 acc[NT][4];
        bf16x8 b0h[NT], b1h[NT], b0l[NT], b1l[NT];
        #pragma unroll
        for (int tl = 0; tl < NT; ++tl) {
            b0h[tl] = *(const bf16x8*)&sHh[tl][buf][hrd0];
            b1h[tl] = *(const bf16x8*)&sHh[tl][buf][hrd1];
            b0l[tl] = *(const bf16x8*)&sHl[tl][buf][hrd0];
            b1l[tl] = *(const bf16x8*)&sHl[tl][buf][hrd1];
            #pragma unroll
            for (int j = 0; j < 4; ++j) acc[tl][j] = bD4[j];
        }
        #pragma unroll
        for (int tl = 0; tl < NT; ++tl)
            #pragma unroll
            for (int j = 0; j < 4; ++j) {
                acc[tl][j] = __builtin_amdgcn_mfma_f32_16x16x32_bf16(bw[j][0].hi, b0l[tl], acc[tl][j], 0, 0, 0);
                acc[tl][j] = __builtin_amdgcn_mfma_f32_16x16x32_bf16(bw[j][1].hi, b1l[tl], acc[tl][j], 0, 0, 0);
                acc[tl][j] = __builtin_amdgcn_mfma_f32_16x16x32_bf16(bw[j][0].lo, b0h[tl], acc[tl][j], 0, 0, 0);
                acc[tl][j] = __builtin_amdgcn_mfma_f32_16x16x32_bf16(bw[j][1].lo, b1h[tl], acc[tl][j], 0, 0, 0);
                acc[tl][j] = __builtin_amdgcn_mfma_f32_16x16x32_bf16(bw[j][0].hi, b0h[tl], acc[tl][j], 0, 0, 0);
                acc[tl][j] = __builtin_amdgcn_mfma_f32_16x16x32_bf16(bw[j][1].hi, b1h[tl], acc[tl][j], 0, 0, 0);
            }
        #pragma unroll
        for (int tl = 0; tl < NT; ++tl) {
            uint_t hhp[2], hlp[2];
            f32x2 pp = {0.f, 0.f};
            #pragma unroll
            for (int rp = 0; rp < 2; ++rp) {
                int r0 = rp * 2, r1 = rp * 2 + 1;
                f32x2 ei = { EXP2F(-acc[tl][0][r0]), EXP2F(-acc[tl][0][r1]) };
                f32x2 ef = { EXP2F(-acc[tl][1][r0]), EXP2F(-acc[tl][1][r1]) };
                f32x2 eg = { EXP2F(-acc[tl][2][r0]), EXP2F(-acc[tl][2][r1]) };
                f32x2 eo = { EXP2F(-acc[tl][3][r0]), EXP2F(-acc[tl][3][r1]) };
                ei = ei + 1.0f; ef = ef + 1.0f; eg = eg + 1.0f; eo = eo + 1.0f;
                f32x2 ig = { RCPF(ei[0]), RCPF(ei[1]) };
                f32x2 fg = { RCPF(ef[0]), RCPF(ef[1]) };
                f32x2 gr = { RCPF(eg[0]), RCPF(eg[1]) };
                f32x2 og = { RCPF(eo[0]), RCPF(eo[1]) };
                f32x2 gg = 2.0f * gr - 1.0f;
                f32x2 cv = { c[tl][r0], c[tl][r1] };
                f32x2 cn = fg * cv + ig * gg;
                c[tl][r0] = cn[0]; c[tl][r1] = cn[1];
                f32x2 ca = cn * (-2.0f * L2E);
                f32x2 ec = { EXP2F(ca[0]), EXP2F(ca[1]) };
                ec = ec + 1.0f;
                f32x2 tr = { RCPF(ec[0]), RCPF(ec[1]) };
                f32x2 th = 2.0f * tr - 1.0f;
                f32x2 hn = og * th;
                pp = pp + wpP[r0] * hn[0];
                pp = pp + wpP[r1] * hn[1];
                uint_t u0 = __float_as_uint(hn[0]);
                uint_t u1 = __float_as_uint(hn[1]);
                f32x2 fh = { __uint_as_float(u0 & 0xffff0000u),
                             __uint_as_float(u1 & 0xffff0000u) };
                hhp[rp] = (u0 >> 16) | (u1 & 0xffff0000u);
                f32x2 lo = hn - fh;
                hlp[rp] = (uint_t)f2bf(lo[0]) | ((uint_t)f2bf(lo[1]) << 16);
            }
            *(u32x2*)&sHh[tl][buf ^ 1][hwr] = u32x2{hhp[0], hhp[1]};
            *(u32x2*)&sHl[tl][buf ^ 1][hwr] = u32x2{hlp[0], hlp[1]};
            sP[tl][buf ^ 1][col * PS + 0  + (w * 4 + quad)] = pp[0];
            sP[tl][buf ^ 1][col * PS + 16 + (w * 4 + quad)] = pp[1];
        }
        __syncthreads();
        buf ^= 1;
        // wave w reduces tile w's projection partials; sP[.][buf] is stable
        // until after the NEXT barrier, which can't be passed before reading.
        if (lane < 32) {
            const float* ppr = &sP[w][buf][prow * PS + pcomp * 16];
            f32x4 v0 = *(const f32x4*)(ppr + 0);
            f32x4 v1 = *(const f32x4*)(ppr + 4);
            f32x4 v2 = *(const f32x4*)(ppr + 8);
            f32x4 v3 = *(const f32x4*)(ppr + 12);
            f32x4 s = (v0 + v1) + (v2 + v3);
            float p = (s[0] + s[1]) + (s[2] + s[3]) + bp;
            out[(size_t)(wg * (NT * 16) + w * 16 + prow) * (DEC_T * 2) + t * 2 + pcomp] = p;
        }
    }
}

extern "C" void kernel_launch(void* const* d_in, const int* in_sizes, int n_in,
                              void* d_out, int out_size, void* d_ws, size_t ws_size,
                              hipStream_t stream) {
    const float* traj = (const float*)d_in[0];
    const float* WihE = (const float*)d_in[1];
    const float* WhhE = (const float*)d_in[2];
    const float* bihE = (const float*)d_in[3];
    const float* bhhE = (const float*)d_in[4];
    const float* WihD = (const float*)d_in[5];
    const float* WhhD = (const float*)d_in[6];
    const float* bihD = (const float*)d_in[7];
    const float* bhhD = (const float*)d_in[8];
    const float* Wpos = (const float*)d_in[9];
    const float* bpos = (const float*)d_in[10];
    float* out = (float*)d_out;

    const int B = in_sizes[0] / (ENC_T * 2);   // 65536
    const int grid = B / (NT * 16);            // 1024 workgroups, 64 rows each

    lstm_seq2seq<<<grid, 256, 0, stream>>>(traj, WihE, WhhE, bihE, bhhE,
                                           WihD, WhhD, bihD, bhhD, Wpos, bpos, out);
}

// Round 9
// 444.470 us; speedup vs baseline: 1.1716x; 1.1716x over previous
//
#include <hip/hip_runtime.h>

#define HID   64
#define ENC_T 20
#define DEC_T 30
#define HS    72   // sH row stride in bf16 elems: 144B = 16B-aligned
#define PS    36   // sP row stride in dwords

typedef __bf16 bf16x8 __attribute__((ext_vector_type(8)));
typedef float  f32x4  __attribute__((ext_vector_type(4)));
typedef float  f32x2  __attribute__((ext_vector_type(2)));
typedef unsigned int u32x2 __attribute__((ext_vector_type(2)));
typedef unsigned short ushort_t;
typedef unsigned int   uint_t;

#if __has_builtin(__builtin_amdgcn_exp2f)
#define EXP2F(x) __builtin_amdgcn_exp2f(x)
#else
#define EXP2F(x) exp2f(x)
#endif
#if __has_builtin(__builtin_amdgcn_rcpf)
#define RCPF(x) __builtin_amdgcn_rcpf(x)
#else
#define RCPF(x) (1.0f / (x))
#endif

#define L2E 1.4426950408889634f

__device__ __forceinline__ ushort_t f2bf(float f) {
    __bf16 b = (__bf16)f;
    union { __bf16 b; ushort_t u; } v; v.b = b; return v.u;
}

struct bfpair { bf16x8 hi, lo; };

// Split 8 consecutive fp32 (scaled by s) into bf16 hi + lo fragments (setup only)
__device__ __forceinline__ bfpair split8s(const float* __restrict__ p, float s) {
    unsigned short h[8], l[8];
    #pragma unroll
    for (int u = 0; u < 8; ++u) {
        float f = p[u] * s;
        __bf16 bh = (__bf16)f;
        h[u] = f2bf(f);
        l[u] = f2bf(f - (float)bh);
    }
    bfpair r;
    __builtin_memcpy(&r.hi, h, 16);
    __builtin_memcpy(&r.lo, l, 16);
    return r;
}

// __launch_bounds__(256,3): the ONLY proven no-spill operating point for this
// working set (R2/R4: 84 VGPR, FETCH ~8MB). Empirical RA law: hint h => RA
// targets ~512/(2h) VGPRs regardless of liveness (h4->64 SPILLS, h5->48
// SPILLS). NT-tiling at hint=1 gave an unexplained correctness failure at
// NT=2 (R8) — that axis is abandoned. FETCH_SIZE is the spill tripwire.
__global__ __launch_bounds__(256, 3)
void lstm_seq2seq(const float* __restrict__ traj,
                  const float* __restrict__ WihE, const float* __restrict__ WhhE,
                  const float* __restrict__ bihE, const float* __restrict__ bhhE,
                  const float* __restrict__ WihD, const float* __restrict__ WhhD,
                  const float* __restrict__ bihD, const float* __restrict__ bhhD,
                  const float* __restrict__ Wpos, const float* __restrict__ bpos,
                  float* __restrict__ out)
{
    __shared__ __align__(16) ushort_t sHh[2][16 * HS];   // h hi [row][unit]
    __shared__ __align__(16) ushort_t sHl[2][16 * HS];   // h lo
    __shared__ __align__(16) float    sX[16 * ENC_T * 2];
    __shared__ __align__(16) float    sP[2][16 * PS];    // projection partials

    const int tid  = threadIdx.x;
    const int w    = tid >> 6;      // wave -> unit tile (units 16w..16w+15)
    const int lane = tid & 63;
    const int col  = lane & 15;     // batch row for this lane
    const int quad = lane >> 4;     // units 16w + quad*4 + r
    const int wg   = blockIdx.x;    // 16 batch rows per block

    const float gsc[4] = { L2E, L2E, 2.0f * L2E, L2E };  // i,f,g(tanh),o pre-scales

    // ---- stage trajectory tile ----
    {
        const float* src = traj + (size_t)wg * (16 * ENC_T * 2);
        #pragma unroll
        for (int i = 0; i < 3; ++i) {
            int idx = tid + i * 256;
            if (idx < 640) sX[idx] = src[idx];
        }
    }
    // ---- zero h buffer 0 ----
    {
        uint_t* hz0 = (uint_t*)&sHh[0][0];
        uint_t* hz1 = (uint_t*)&sHl[0][0];
        for (int j = tid; j < 16 * HS / 2; j += 256) { hz0[j] = 0; hz1[j] = 0; }
    }

    // ---- encoder per-lane constants ----
    float wi0[4][4], wi1[4][4], bE[4][4];
    #pragma unroll
    for (int j = 0; j < 4; ++j)
        #pragma unroll
        for (int r = 0; r < 4; ++r) {
            int g = 64 * j + 16 * w + quad * 4 + r;
            wi0[j][r] = WihE[g * 2 + 0] * gsc[j];
            wi1[j][r] = WihE[g * 2 + 1] * gsc[j];
            bE[j][r]  = (bihE[g] + bhhE[g]) * gsc[j];
        }

    // ---- encoder W_hh A-fragments: A[m][k] ----
    bfpair bw[4][2];
    #pragma unroll
    for (int j = 0; j < 4; ++j) {
        int g = 64 * j + 16 * w + col;
        #pragma unroll
        for (int kb = 0; kb < 2; ++kb)
            bw[j][kb] = split8s(WhhE + g * 64 + kb * 32 + quad * 8, gsc[j]);
    }

    float c[4] = {0.f, 0.f, 0.f, 0.f};
    int buf = 0;
    const int hwr = col * HS + 16 * w + quad * 4;   // h write offset (elems)

    __syncthreads();

    // =========================== ENCODER ===========================
    for (int t = 0; t < ENC_T; ++t) {
        f32x4 acc[4];
        {
            f32x2 xp = *(const f32x2*)&sX[col * (ENC_T * 2) + 2 * t];
            #pragma unroll
            for (int j = 0; j < 4; ++j)
                #pragma unroll
                for (int r = 0; r < 4; ++r)
                    acc[j][r] = fmaf(wi1[j][r], xp[1], fmaf(wi0[j][r], xp[0], bE[j][r]));
        }
        bf16x8 b0h = *(const bf16x8*)&sHh[buf][col * HS +  0 + quad * 8];
        bf16x8 b1h = *(const bf16x8*)&sHh[buf][col * HS + 32 + quad * 8];
        bf16x8 b0l = *(const bf16x8*)&sHl[buf][col * HS +  0 + quad * 8];
        bf16x8 b1l = *(const bf16x8*)&sHl[buf][col * HS + 32 + quad * 8];
        #pragma unroll
        for (int j = 0; j < 4; ++j) {
            acc[j] = __builtin_amdgcn_mfma_f32_16x16x32_bf16(bw[j][0].hi, b0l, acc[j], 0, 0, 0);
            acc[j] = __builtin_amdgcn_mfma_f32_16x16x32_bf16(bw[j][1].hi, b1l, acc[j], 0, 0, 0);
            acc[j] = __builtin_amdgcn_mfma_f32_16x16x32_bf16(bw[j][0].lo, b0h, acc[j], 0, 0, 0);
            acc[j] = __builtin_amdgcn_mfma_f32_16x16x32_bf16(bw[j][1].lo, b1h, acc[j], 0, 0, 0);
            acc[j] = __builtin_amdgcn_mfma_f32_16x16x32_bf16(bw[j][0].hi, b0h, acc[j], 0, 0, 0);
            acc[j] = __builtin_amdgcn_mfma_f32_16x16x32_bf16(bw[j][1].hi, b1h, acc[j], 0, 0, 0);
        }
        // packed elementwise on r-pairs
        uint_t hhp[2], hlp[2];
        #pragma unroll
        for (int rp = 0; rp < 2; ++rp) {
            int r0 = rp * 2, r1 = rp * 2 + 1;
            f32x2 ei = { EXP2F(-acc[0][r0]), EXP2F(-acc[0][r1]) };
            f32x2 ef = { EXP2F(-acc[1][r0]), EXP2F(-acc[1][r1]) };
            f32x2 eg = { EXP2F(-acc[2][r0]), EXP2F(-acc[2][r1]) };
            f32x2 eo = { EXP2F(-acc[3][r0]), EXP2F(-acc[3][r1]) };
            ei = ei + 1.0f; ef = ef + 1.0f; eg = eg + 1.0f; eo = eo + 1.0f;
            f32x2 ig = { RCPF(ei[0]), RCPF(ei[1]) };
            f32x2 fg = { RCPF(ef[0]), RCPF(ef[1]) };
            f32x2 gr = { RCPF(eg[0]), RCPF(eg[1]) };
            f32x2 og = { RCPF(eo[0]), RCPF(eo[1]) };
            f32x2 gg = 2.0f * gr - 1.0f;
            f32x2 cv = { c[r0], c[r1] };
            f32x2 cn = fg * cv + ig * gg;
            c[r0] = cn[0]; c[r1] = cn[1];
            f32x2 ca = cn * (-2.0f * L2E);
            f32x2 ec = { EXP2F(ca[0]), EXP2F(ca[1]) };
            ec = ec + 1.0f;
            f32x2 tr = { RCPF(ec[0]), RCPF(ec[1]) };
            f32x2 th = 2.0f * tr - 1.0f;
            f32x2 hn = og * th;
            // truncation hi/lo split + pack
            uint_t b0 = __float_as_uint(hn[0]);
            uint_t b1 = __float_as_uint(hn[1]);
            f32x2 fh = { __uint_as_float(b0 & 0xffff0000u),
                         __uint_as_float(b1 & 0xffff0000u) };
            hhp[rp] = (b0 >> 16) | (b1 & 0xffff0000u);
            f32x2 lo = hn - fh;
            hlp[rp] = (uint_t)f2bf(lo[0]) | ((uint_t)f2bf(lo[1]) << 16);
        }
        *(u32x2*)&sHh[buf ^ 1][hwr] = u32x2{hhp[0], hhp[1]};
        *(u32x2*)&sHl[buf ^ 1][hwr] = u32x2{hlp[0], hlp[1]};
        __syncthreads();
        buf ^= 1;
    }

    // ---- decoder combined weights ----
    f32x4 bD4[4];
    #pragma unroll
    for (int j = 0; j < 4; ++j) {
        #pragma unroll
        for (int r = 0; r < 4; ++r) {
            int g = 64 * j + 16 * w + quad * 4 + r;
            bD4[j][r] = (bihD[g] + bhhD[g]) * gsc[j];
        }
        int g = 64 * j + 16 * w + col;
        #pragma unroll
        for (int kb = 0; kb < 2; ++kb) {
            int off = g * 64 + kb * 32 + quad * 8;
            float tmp[8];
            #pragma unroll
            for (int u = 0; u < 8; ++u) tmp[u] = WihD[off + u] + WhhD[off + u];
            bw[j][kb] = split8s(tmp, gsc[j]);
        }
    }

    // projection constants: this lane's 4 units -> {comp0, comp1} pairs
    f32x2 wpP[4];
    #pragma unroll
    for (int r = 0; r < 4; ++r) {
        int u = 16 * w + quad * 4 + r;
        wpP[r] = f32x2{ Wpos[u], Wpos[64 + u] };
    }
    const int prow  = lane & 15;
    const int pcomp = (lane >> 4) & 1;
    const float bp  = bpos[pcomp];

    // =========================== DECODER ===========================
    for (int t = 0; t < DEC_T; ++t) {
        f32x4 acc[4];
        #pragma unroll
        for (int j = 0; j < 4; ++j) acc[j] = bD4[j];
        bf16x8 b0h = *(const bf16x8*)&sHh[buf][col * HS +  0 + quad * 8];
        bf16x8 b1h = *(const bf16x8*)&sHh[buf][col * HS + 32 + quad * 8];
        bf16x8 b0l = *(const bf16x8*)&sHl[buf][col * HS +  0 + quad * 8];
        bf16x8 b1l = *(const bf16x8*)&sHl[buf][col * HS + 32 + quad * 8];
        #pragma unroll
        for (int j = 0; j < 4; ++j) {
            acc[j] = __builtin_amdgcn_mfma_f32_16x16x32_bf16(bw[j][0].hi, b0l, acc[j], 0, 0, 0);
            acc[j] = __builtin_amdgcn_mfma_f32_16x16x32_bf16(bw[j][1].hi, b1l, acc[j], 0, 0, 0);
            acc[j] = __builtin_amdgcn_mfma_f32_16x16x32_bf16(bw[j][0].lo, b0h, acc[j], 0, 0, 0);
            acc[j] = __builtin_amdgcn_mfma_f32_16x16x32_bf16(bw[j][1].lo, b1h, acc[j], 0, 0, 0);
            acc[j] = __builtin_amdgcn_mfma_f32_16x16x32_bf16(bw[j][0].hi, b0h, acc[j], 0, 0, 0);
            acc[j] = __builtin_amdgcn_mfma_f32_16x16x32_bf16(bw[j][1].hi, b1h, acc[j], 0, 0, 0);
        }
        uint_t hhp[2], hlp[2];
        f32x2 pp = {0.f, 0.f};
        #pragma unroll
        for (int rp = 0; rp < 2; ++rp) {
            int r0 = rp * 2, r1 = rp * 2 + 1;
            f32x2 ei = { EXP2F(-acc[0][r0]), EXP2F(-acc[0][r1]) };
            f32x2 ef = { EXP2F(-acc[1][r0]), EXP2F(-acc[1][r1]) };
            f32x2 eg = { EXP2F(-acc[2][r0]), EXP2F(-acc[2][r1]) };
            f32x2 eo = { EXP2F(-acc[3][r0]), EXP2F(-acc[3][r1]) };
            ei = ei + 1.0f; ef = ef + 1.0f; eg = eg + 1.0f; eo = eo + 1.0f;
            f32x2 ig = { RCPF(ei[0]), RCPF(ei[1]) };
            f32x2 fg = { RCPF(ef[0]), RCPF(ef[1]) };
            f32x2 gr = { RCPF(eg[0]), RCPF(eg[1]) };
            f32x2 og = { RCPF(eo[0]), RCPF(eo[1]) };
            f32x2 gg = 2.0f * gr - 1.0f;
            f32x2 cv = { c[r0], c[r1] };
            f32x2 cn = fg * cv + ig * gg;
            c[r0] = cn[0]; c[r1] = cn[1];
            f32x2 ca = cn * (-2.0f * L2E);
            f32x2 ec = { EXP2F(ca[0]), EXP2F(ca[1]) };
            ec = ec + 1.0f;
            f32x2 tr = { RCPF(ec[0]), RCPF(ec[1]) };
            f32x2 th = 2.0f * tr - 1.0f;
            f32x2 hn = og * th;
            pp = pp + wpP[r0] * hn[0];
            pp = pp + wpP[r1] * hn[1];
            uint_t b0 = __float_as_uint(hn[0]);
            uint_t b1 = __float_as_uint(hn[1]);
            f32x2 fh = { __uint_as_float(b0 & 0xffff0000u),
                         __uint_as_float(b1 & 0xffff0000u) };
            hhp[rp] = (b0 >> 16) | (b1 & 0xffff0000u);
            f32x2 lo = hn - fh;
            hlp[rp] = (uint_t)f2bf(lo[0]) | ((uint_t)f2bf(lo[1]) << 16);
        }
        *(u32x2*)&sHh[buf ^ 1][hwr] = u32x2{hhp[0], hhp[1]};
        *(u32x2*)&sHl[buf ^ 1][hwr] = u32x2{hlp[0], hlp[1]};
        sP[buf ^ 1][col * PS + 0  + (w * 4 + quad)] = pp[0];
        sP[buf ^ 1][col * PS + 16 + (w * 4 + quad)] = pp[1];
        __syncthreads();
        buf ^= 1;
        // wave 0 reduces this step's projection partials; sP[buf] is stable
        // until after the NEXT barrier, which can't be passed before reading.
        if (w == 0 && lane < 32) {
            const float* ppr = &sP[buf][prow * PS + pcomp * 16];
            f32x4 v0 = *(const f32x4*)(ppr + 0);
            f32x4 v1 = *(const f32x4*)(ppr + 4);
            f32x4 v2 = *(const f32x4*)(ppr + 8);
            f32x4 v3 = *(const f32x4*)(ppr + 12);
            f32x4 s = (v0 + v1) + (v2 + v3);
            float p = (s[0] + s[1]) + (s[2] + s[3]) + bp;
            out[(size_t)(wg * 16 + prow) * (DEC_T * 2) + t * 2 + pcomp] = p;
        }
    }
}

extern "C" void kernel_launch(void* const* d_in, const int* in_sizes, int n_in,
                              void* d_out, int out_size, void* d_ws, size_t ws_size,
                              hipStream_t stream) {
    const float* traj = (const float*)d_in[0];
    const float* WihE = (const float*)d_in[1];
    const float* WhhE = (const float*)d_in[2];
    const float* bihE = (const float*)d_in[3];
    const float* bhhE = (const float*)d_in[4];
    const float* WihD = (const float*)d_in[5];
    const float* WhhD = (const float*)d_in[6];
    const float* bihD = (const float*)d_in[7];
    const float* bhhD = (const float*)d_in[8];
    const float* Wpos = (const float*)d_in[9];
    const float* bpos = (const float*)d_in[10];
    float* out = (float*)d_out;

    const int B = in_sizes[0] / (ENC_T * 2);   // 65536
    const int grid = B / 16;                   // 4096 workgroups, 16 rows each

    lstm_seq2seq<<<grid, 256, 0, stream>>>(traj, WihE, WhhE, bihE, bhhE,
                                           WihD, WhhD, bihD, bhhD, Wpos, bpos, out);
}